// Round 1
// baseline (426.178 us; speedup 1.0000x reference)
//
#include <hip/hip_runtime.h>
#include <hip/hip_bf16.h>
#include <stdint.h>

typedef float f32x4 __attribute__((ext_vector_type(4)));
typedef __bf16 bf16x8 __attribute__((ext_vector_type(8)));

#define NB 8
#define NC 192
#define NO 576
#define NH 128
#define NWID 128
#define NSP 16384
#define NHEADS 4
#define NCH 48

// workspace layout (bytes)
#define OFF_KV    0u
#define OFF_BIAS  12288u
#define OFF_SSQ   30720u
#define OFF_S     43008u
#define OFF_WP    337920u
#define OFF_M     2107392u
#define OFF_QKV1  2697216u
#define OFF_QKV2  153692160u

// ---------------- kernel 1: kv = prior @ w_kernel^T  (8 x 384) ----------------
__global__ void k_kv(const float* __restrict__ prior, const float* __restrict__ w_kernel,
                     float* __restrict__ kv) {
    int t = blockIdx.x * 256 + threadIdx.x;
    if (t >= NB * 384) return;
    int b = t / 384, j = t % 384;
    const float* p = prior + b * NC;
    const float* wk = w_kernel + j * NC;
    float s = 0.f;
    for (int f = 0; f < NC; ++f) s += p[f] * wk[f];
    kv[t] = s;
}

// ---------------- kernel 2: fold affine into weights: Wp, bias ----------------
__global__ void k_prep(const float* __restrict__ w_qkv, const float* __restrict__ kv,
                       __bf16* __restrict__ Wp, float* __restrict__ bias) {
    int b = blockIdx.x / NO, o = blockIdx.x % NO;
    int l = threadIdx.x; // 64 threads = 1 wave
    const float* kvb = kv + b * 384;
    float part = 0.f;
    for (int i = 0; i < 3; ++i) {
        int c = l + i * 64;
        float wq = w_qkv[o * NC + c];
        Wp[(size_t)(b * NO + o) * NC + c] = (__bf16)(wq * kvb[c]);
        part += wq * kvb[192 + c];
    }
    for (int off = 32; off > 0; off >>= 1) part += __shfl_down(part, off);
    if (l == 0) bias[b * NO + o] = part;
}

// ---------------- kernel 3: qkv GEMM: qkv1[b,o,n] = bias + sum_c Wp[b,o,c]*x[b,c,n] ----------------
__global__ __launch_bounds__(256) void k_qkv(const float* __restrict__ x, const __bf16* __restrict__ Wp,
                                             const float* __restrict__ bias, __bf16* __restrict__ qkv1) {
    int b = blockIdx.z;
    int o0 = blockIdx.x * 64;
    int n0blk = blockIdx.y * 128;
    __shared__ __align__(16) __bf16 lds[64 * 200]; // 64 rows x 192, padded stride 200 (400B: 16B-aligned, bank-spread)
    int tid = threadIdx.x;
    const __bf16* wsrc = Wp + (size_t)(b * NO + o0) * NC;
    for (int i = 0; i < 6; ++i) {
        int ch = tid + i * 256;               // 1536 chunks of 8 bf16
        int r = ch / 24, c8 = (ch % 24) * 8;
        bf16x8 v = *reinterpret_cast<const bf16x8*>(wsrc + r * NC + c8);
        *reinterpret_cast<bf16x8*>(&lds[r * 200 + c8]) = v;
    }
    __syncthreads();
    int w = tid >> 6, l = tid & 63, lr = l & 15, lg = l >> 4;
    int n0 = n0blk + w * 32;
    f32x4 acc[4][2] = {};
    for (int ks = 0; ks < 6; ++ks) {
        int k0 = ks * 32;
        bf16x8 a[4];
        for (int mf = 0; mf < 4; ++mf)
            a[mf] = *reinterpret_cast<const bf16x8*>(&lds[(mf * 16 + lr) * 200 + k0 + lg * 8]);
        bf16x8 bb[2];
        for (int nf = 0; nf < 2; ++nf) {
            const float* xp = x + (size_t)(b * NC + k0 + lg * 8) * NSP + n0 + nf * 16 + lr;
            bf16x8 t;
            for (int j = 0; j < 8; ++j) t[j] = (__bf16)xp[(size_t)j * NSP];
            bb[nf] = t;
        }
        for (int mf = 0; mf < 4; ++mf)
            for (int nf = 0; nf < 2; ++nf)
                acc[mf][nf] = __builtin_amdgcn_mfma_f32_16x16x32_bf16(a[mf], bb[nf], acc[mf][nf], 0, 0, 0);
    }
    const float* bb2 = bias + b * NO + o0;
    for (int mf = 0; mf < 4; ++mf)
        for (int r = 0; r < 4; ++r) {
            int orow = mf * 16 + lg * 4 + r;
            float bv = bb2[orow];
            for (int nf = 0; nf < 2; ++nf) {
                int n = n0 + nf * 16 + lr;
                qkv1[(size_t)(b * NO + o0 + orow) * NSP + n] = (__bf16)(acc[mf][nf][r] + bv);
            }
        }
}

// ---------------- kernel 4: depthwise 3x3 conv + sumsq(q,k) ----------------
__global__ __launch_bounds__(256) void k_dw(const __bf16* __restrict__ qkv1, const float* __restrict__ w_dw,
                                            __bf16* __restrict__ qkv2, float* __restrict__ ssq) {
    int b = blockIdx.z, o = blockIdx.y, ys = blockIdx.x * 8;
    __shared__ float lin[10][128];
    int tid = threadIdx.x;
    const __bf16* src = qkv1 + (size_t)(b * NO + o) * NSP;
    if (tid < 160) {
        int ry = tid / 16, cx = (tid % 16) * 8;
        int y = ys - 1 + ry;
        if (y >= 0 && y < NH) {
            bf16x8 v = *reinterpret_cast<const bf16x8*>(src + y * NWID + cx);
            for (int j = 0; j < 8; ++j) lin[ry][cx + j] = (float)v[j];
        } else {
            for (int j = 0; j < 8; ++j) lin[ry][cx + j] = 0.f;
        }
    }
    __syncthreads();
    float wd[9];
    for (int i = 0; i < 9; ++i) wd[i] = w_dw[o * 9 + i];
    float ss = 0.f;
    for (int i = 0; i < 4; ++i) {
        int idx = tid + i * 256;
        int oy = idx >> 7, ox = idx & 127;
        float s = 0.f;
        for (int dy = 0; dy < 3; ++dy)
            for (int dx = 0; dx < 3; ++dx) {
                int xx = ox + dx - 1;
                float v = (xx >= 0 && xx < NWID) ? lin[oy + dy][xx] : 0.f;
                s += v * wd[dy * 3 + dx];
            }
        __bf16 sb = (__bf16)s;
        qkv2[(size_t)(b * NO + o) * NSP + (ys + oy) * NWID + ox] = sb;
        if (o < 384) { float sf = (float)sb; ss += sf * sf; }
    }
    if (o < 384) {
        for (int off = 32; off > 0; off >>= 1) ss += __shfl_down(ss, off);
        if ((tid & 63) == 0) atomicAdd(&ssq[b * 384 + o], ss);
    }
}

// ---------------- kernel 5: raw Gram dots S[b,h,c,d] = sum_n q_c k_d ----------------
__global__ __launch_bounds__(256) void k_sdot(const __bf16* __restrict__ qkv2, float* __restrict__ S) {
    int b = blockIdx.z, h = blockIdx.y;
    int tid = threadIdx.x, w = tid >> 6, l = tid & 63, lr = l & 15, lg = l >> 4;
    f32x4 acc[3][3] = {};
    const __bf16* qbase = qkv2 + (size_t)(b * NO + h * NCH) * NSP;
    const __bf16* kbase = qkv2 + (size_t)(b * NO + 192 + h * NCH) * NSP;
    int nb0 = blockIdx.x * 1024 + w * 256;
    for (int ks = 0; ks < 8; ++ks) {
        int nb = nb0 + ks * 32 + lg * 8;
        bf16x8 a[3], bb[3];
        for (int mf = 0; mf < 3; ++mf)
            a[mf] = *reinterpret_cast<const bf16x8*>(qbase + (size_t)(mf * 16 + lr) * NSP + nb);
        for (int nf = 0; nf < 3; ++nf)
            bb[nf] = *reinterpret_cast<const bf16x8*>(kbase + (size_t)(nf * 16 + lr) * NSP + nb);
        for (int mf = 0; mf < 3; ++mf)
            for (int nf = 0; nf < 3; ++nf)
                acc[mf][nf] = __builtin_amdgcn_mfma_f32_16x16x32_bf16(a[mf], bb[nf], acc[mf][nf], 0, 0, 0);
    }
    __shared__ float red[4][48][49];
    for (int mf = 0; mf < 3; ++mf)
        for (int nf = 0; nf < 3; ++nf)
            for (int r = 0; r < 4; ++r) {
                int c = mf * 16 + lg * 4 + r, d = nf * 16 + lr;
                red[w][c][d] = acc[mf][nf][r];
            }
    __syncthreads();
    float* Sb = S + (size_t)(b * NHEADS + h) * NCH * NCH;
    for (int i = 0; i < 9; ++i) {
        int idx = tid + i * 256;
        int c = idx / 48, d = idx % 48;
        float s = red[0][c][d] + red[1][c][d] + red[2][c][d] + red[3][c][d];
        atomicAdd(&Sb[c * 48 + d], s);
    }
}

// ---------------- kernel 6: normalize + softmax + fold proj: M[b] = w_proj @ blockdiag(attn) ----------------
__global__ __launch_bounds__(256) void k_soft(const float* __restrict__ S, const float* __restrict__ ssq,
                                              const float* __restrict__ temp, const float* __restrict__ w_proj,
                                              __bf16* __restrict__ M) {
    int b = blockIdx.x / NHEADS, h = blockIdx.x % NHEADS;
    int tid = threadIdx.x;
    __shared__ float attn[48][48];
    __shared__ float inv[96];
    if (tid < 96) {
        int c = tid % 48;
        int isK = tid / 48;
        float v = ssq[b * 384 + isK * 192 + h * NCH + c];
        float nrm = fmaxf(sqrtf(v), 1e-12f);
        inv[tid] = 1.f / nrm;
    }
    __syncthreads();
    float tp = temp[h];
    const float* Sb = S + (size_t)(b * NHEADS + h) * NCH * NCH;
    for (int i = 0; i < 9; ++i) {
        int idx = tid + i * 256;
        int c = idx / 48, d = idx % 48;
        attn[c][d] = Sb[c * 48 + d] * inv[c] * inv[48 + d] * tp;
    }
    __syncthreads();
    if (tid < 48) {
        float m = -1e30f;
        for (int d = 0; d < 48; ++d) m = fmaxf(m, attn[tid][d]);
        float sum = 0.f;
        for (int d = 0; d < 48; ++d) { float e = __expf(attn[tid][d] - m); attn[tid][d] = e; sum += e; }
        float r = 1.f / sum;
        for (int d = 0; d < 48; ++d) attn[tid][d] *= r;
    }
    __syncthreads();
    for (int i = 0; i < 36; ++i) {
        int idx = tid + i * 256;
        int o = idx / 48, d = idx % 48;
        const float* wp = w_proj + o * NC + h * NCH;
        float s = 0.f;
        for (int c = 0; c < 48; ++c) s += wp[c] * attn[c][d];
        M[(size_t)(b * NC + o) * NC + h * NCH + d] = (__bf16)s;
    }
}

// ---------------- kernel 7: final GEMM: out[b,o,n] = sum_c' M[b,o,c'] * v[b,c',n] ----------------
__global__ __launch_bounds__(256) void k_out(const __bf16* __restrict__ Mw, const __bf16* __restrict__ qkv2,
                                             float* __restrict__ outp) {
    int b = blockIdx.z;
    int o0 = blockIdx.x * 64;
    int n0blk = blockIdx.y * 128;
    __shared__ __align__(16) __bf16 lds[64 * 200];
    int tid = threadIdx.x;
    const __bf16* msrc = Mw + (size_t)(b * NC + o0) * NC;
    for (int i = 0; i < 6; ++i) {
        int ch = tid + i * 256;
        int r = ch / 24, c8 = (ch % 24) * 8;
        bf16x8 v = *reinterpret_cast<const bf16x8*>(msrc + r * NC + c8);
        *reinterpret_cast<bf16x8*>(&lds[r * 200 + c8]) = v;
    }
    __syncthreads();
    int w = tid >> 6, l = tid & 63, lr = l & 15, lg = l >> 4;
    int n0 = n0blk + w * 32;
    const __bf16* vbase = qkv2 + (size_t)(b * NO + 384) * NSP;
    f32x4 acc[4][2] = {};
    for (int ks = 0; ks < 6; ++ks) {
        int k0 = ks * 32;
        bf16x8 a[4];
        for (int mf = 0; mf < 4; ++mf)
            a[mf] = *reinterpret_cast<const bf16x8*>(&lds[(mf * 16 + lr) * 200 + k0 + lg * 8]);
        bf16x8 bb[2];
        for (int nf = 0; nf < 2; ++nf) {
            const __bf16* vp = vbase + (size_t)(k0 + lg * 8) * NSP + n0 + nf * 16 + lr;
            bf16x8 t;
            for (int j = 0; j < 8; ++j) t[j] = vp[(size_t)j * NSP];
            bb[nf] = t;
        }
        for (int mf = 0; mf < 4; ++mf)
            for (int nf = 0; nf < 2; ++nf)
                acc[mf][nf] = __builtin_amdgcn_mfma_f32_16x16x32_bf16(a[mf], bb[nf], acc[mf][nf], 0, 0, 0);
    }
    for (int mf = 0; mf < 4; ++mf)
        for (int r = 0; r < 4; ++r) {
            int orow = o0 + mf * 16 + lg * 4 + r;
            for (int nf = 0; nf < 2; ++nf) {
                int n = n0 + nf * 16 + lr;
                outp[(size_t)(b * NC + orow) * NSP + n] = acc[mf][nf][r];
            }
        }
}

extern "C" void kernel_launch(void* const* d_in, const int* in_sizes, int n_in,
                              void* d_out, int out_size, void* d_ws, size_t ws_size,
                              hipStream_t stream) {
    const float* x        = (const float*)d_in[0];
    const float* prior    = (const float*)d_in[1];
    const float* w_qkv    = (const float*)d_in[2];
    const float* w_dw     = (const float*)d_in[3];
    const float* w_proj   = (const float*)d_in[4];
    const float* w_kernel = (const float*)d_in[5];
    const float* temp     = (const float*)d_in[6];
    char* ws = (char*)d_ws;
    float*  kv    = (float*)(ws + OFF_KV);
    float*  bias  = (float*)(ws + OFF_BIAS);
    float*  ssq   = (float*)(ws + OFF_SSQ);
    float*  S     = (float*)(ws + OFF_S);
    __bf16* Wp    = (__bf16*)(ws + OFF_WP);
    __bf16* M     = (__bf16*)(ws + OFF_M);
    __bf16* qkv1  = (__bf16*)(ws + OFF_QKV1);
    __bf16* qkv2  = (__bf16*)(ws + OFF_QKV2);
    float*  outp  = (float*)d_out;

    // zero atomic accumulators (ssq + S are contiguous)
    hipMemsetAsync(ws + OFF_SSQ, 0, 12288 + 294912, stream);

    k_kv<<<12, 256, 0, stream>>>(prior, w_kernel, kv);
    k_prep<<<NB * NO, 64, 0, stream>>>(w_qkv, kv, Wp, bias);
    k_qkv<<<dim3(9, 128, 8), 256, 0, stream>>>(x, Wp, bias, qkv1);
    k_dw<<<dim3(16, 576, 8), 256, 0, stream>>>(qkv1, w_dw, qkv2, ssq);
    k_sdot<<<dim3(16, 4, 8), 256, 0, stream>>>(qkv2, S);
    k_soft<<<32, 256, 0, stream>>>(S, ssq, temp, w_proj, M);
    k_out<<<dim3(3, 128, 8), 256, 0, stream>>>(M, qkv2, outp);
}

// Round 2
// 358.394 us; speedup vs baseline: 1.1891x; 1.1891x over previous
//
#include <hip/hip_runtime.h>
#include <hip/hip_bf16.h>
#include <stdint.h>

typedef float f32x4 __attribute__((ext_vector_type(4)));
typedef __bf16 bf16x8 __attribute__((ext_vector_type(8)));
typedef __bf16 bf16x2 __attribute__((ext_vector_type(2)));

#define NB 8
#define NC 192
#define NO 576
#define NH 128
#define NWID 128
#define NSP 16384
#define NHEADS 4
#define NCH 48

// workspace layout (bytes)
#define OFF_KV    0u
#define OFF_SSQ   12288u
#define OFF_S     24576u        // 294912 B
#define OFF_WB    319488u       // 221184 B
#define OFF_M     540672u       // 589824 B
#define OFF_XT    1130496u      // xt: 50331648 B; qkv2 aliases this region (xt dead by then): 150994944 B
#define OFF_QKV1  152125440u    // 150994944 B -> end 303120384

// ---------------- kernel 1: kv = prior @ w_kernel^T  (8 x 384) ----------------
__global__ void k_kv(const float* __restrict__ prior, const float* __restrict__ w_kernel,
                     float* __restrict__ kv) {
    int t = blockIdx.x * 256 + threadIdx.x;
    if (t >= NB * 384) return;
    int b = t / 384, j = t % 384;
    const float* p = prior + b * NC;
    const float* wk = w_kernel + j * NC;
    float s = 0.f;
    for (int f = 0; f < NC; ++f) s += p[f] * wk[f];
    kv[t] = s;
}

// ---------------- kernel 2: cast w_qkv -> bf16 (batch-independent now) ----------------
__global__ void k_wcast(const float* __restrict__ w_qkv, __bf16* __restrict__ Wb) {
    int t = blockIdx.x * 256 + threadIdx.x;
    if (t < NO * NC) Wb[t] = (__bf16)w_qkv[t];
}

// ---------------- kernel 3: x~ = x*kv1 + kv2, transposed to [b][n][c] bf16 ----------------
__global__ __launch_bounds__(256) void k_xt(const float* __restrict__ x, const float* __restrict__ kv,
                                            __bf16* __restrict__ xt) {
    int b = blockIdx.y;
    int n0 = blockIdx.x * 128;
    __shared__ __align__(16) __bf16 lds[128][200];
    int t = threadIdx.x;
    for (int p = 0; p < 24; ++p) {
        int id = p * 256 + t;
        int c = id / 32, n4 = (id % 32) * 4;
        f32x4 v = *reinterpret_cast<const f32x4*>(x + (size_t)(b * NC + c) * NSP + n0 + n4);
        float k1 = kv[b * 384 + c], k2 = kv[b * 384 + 192 + c];
        for (int j = 0; j < 4; ++j) lds[n4 + j][c] = (__bf16)(v[j] * k1 + k2);
    }
    __syncthreads();
    for (int p = 0; p < 12; ++p) {
        int id = p * 256 + t;
        int n = id / 24, c8 = (id % 24) * 8;
        bf16x8 r = *reinterpret_cast<const bf16x8*>(&lds[n][c8]);
        *reinterpret_cast<bf16x8*>(xt + (size_t)(b * NSP + n0 + n) * NC + c8) = r;
    }
}

// ---------------- kernel 4: qkv GEMM, no LDS: qkv1[b,o,n] = sum_c Wb[o,c]*xt[b,n,c] ----------------
__global__ __launch_bounds__(256) void k_qkv(const __bf16* __restrict__ xt, const __bf16* __restrict__ Wb,
                                             __bf16* __restrict__ qkv1) {
    int b = blockIdx.z;
    int o0 = blockIdx.x * 64;
    int tid = threadIdx.x, w = tid >> 6, l = tid & 63, lr = l & 15, lg = l >> 4;
    int n0 = blockIdx.y * 128 + w * 32;
    const __bf16* abase = Wb + (size_t)(o0 + lr) * NC + lg * 8;
    const __bf16* bbase = xt + (size_t)(b * NSP + n0 + lr) * NC + lg * 8;
    f32x4 acc[4][2] = {};
    for (int ks = 0; ks < 6; ++ks) {
        bf16x8 a[4], bb[2];
        for (int mf = 0; mf < 4; ++mf)
            a[mf] = *reinterpret_cast<const bf16x8*>(abase + (size_t)mf * 16 * NC + ks * 32);
        for (int nf = 0; nf < 2; ++nf)
            bb[nf] = *reinterpret_cast<const bf16x8*>(bbase + (size_t)nf * 16 * NC + ks * 32);
        for (int mf = 0; mf < 4; ++mf)
            for (int nf = 0; nf < 2; ++nf)
                acc[mf][nf] = __builtin_amdgcn_mfma_f32_16x16x32_bf16(a[mf], bb[nf], acc[mf][nf], 0, 0, 0);
    }
    for (int mf = 0; mf < 4; ++mf)
        for (int r = 0; r < 4; ++r) {
            int orow = o0 + mf * 16 + lg * 4 + r;
            for (int nf = 0; nf < 2; ++nf)
                qkv1[(size_t)(b * NO + orow) * NSP + n0 + nf * 16 + lr] = (__bf16)acc[mf][nf][r];
        }
}

// ---------------- kernel 5: depthwise 3x3 conv + sumsq(q,k), register-rolling ----------------
__global__ __launch_bounds__(256) void k_dw(const __bf16* __restrict__ qkv1, const float* __restrict__ w_dw,
                                            __bf16* __restrict__ qkv2, float* __restrict__ ssq) {
    int task = blockIdx.x * 4 + (threadIdx.x >> 6);
    int l = threadIdx.x & 63;
    int strip = task & 7;          // 8 strips x 16 rows
    int bo = task >> 3;            // b*576 + o
    int o = bo % NO, b = bo / NO;
    const __bf16* src = qkv1 + (size_t)bo * NSP;
    __bf16* dst = qkv2 + (size_t)bo * NSP;
    float wd[9];
#pragma unroll
    for (int i = 0; i < 9; ++i) wd[i] = w_dw[o * 9 + i];
    int ys = strip * 16;
    float a0, b0, L0, R0, a1, b1, L1, R1, a2, b2, L2, R2;

#define LOADROW(Y, A, B, L_, R_) {                                            \
        bf16x2 p = {};                                                        \
        int y_ = (Y);                                                         \
        if (y_ >= 0 && y_ < NH) p = *reinterpret_cast<const bf16x2*>(src + y_ * NWID + 2 * l); \
        A = (float)p[0]; B = (float)p[1];                                     \
        L_ = __shfl(B, l - 1); R_ = __shfl(A, l + 1);                         \
        if (l == 0) L_ = 0.f;                                                 \
        if (l == 63) R_ = 0.f; }

    LOADROW(ys - 1, a0, b0, L0, R0)
    LOADROW(ys,     a1, b1, L1, R1)
    float ss = 0.f;
    bool qk = (o < 384);
#pragma unroll 4
    for (int i = 0; i < 16; ++i) {
        LOADROW(ys + i + 1, a2, b2, L2, R2)
        float oa = L0 * wd[0] + a0 * wd[1] + b0 * wd[2]
                 + L1 * wd[3] + a1 * wd[4] + b1 * wd[5]
                 + L2 * wd[6] + a2 * wd[7] + b2 * wd[8];
        float ob = a0 * wd[0] + b0 * wd[1] + R0 * wd[2]
                 + a1 * wd[3] + b1 * wd[4] + R1 * wd[5]
                 + a2 * wd[6] + b2 * wd[7] + R2 * wd[8];
        bf16x2 ov; ov[0] = (__bf16)oa; ov[1] = (__bf16)ob;
        *reinterpret_cast<bf16x2*>(dst + (ys + i) * NWID + 2 * l) = ov;
        if (qk) { float fa = (float)ov[0], fb = (float)ov[1]; ss += fa * fa + fb * fb; }
        a0 = a1; b0 = b1; L0 = L1; R0 = R1;
        a1 = a2; b1 = b2; L1 = L2; R1 = R2;
    }
#undef LOADROW
    if (qk) {
        for (int off = 32; off > 0; off >>= 1) ss += __shfl_down(ss, off);
        if (l == 0) atomicAdd(&ssq[b * 384 + o], ss);
    }
}

// ---------------- kernel 6: raw Gram dots S[b,h,c,d] = sum_n q_c k_d ----------------
__global__ __launch_bounds__(256) void k_sdot(const __bf16* __restrict__ qkv2, float* __restrict__ S) {
    int b = blockIdx.z, h = blockIdx.y;
    int tid = threadIdx.x, w = tid >> 6, l = tid & 63, lr = l & 15, lg = l >> 4;
    f32x4 acc[3][3] = {};
    const __bf16* qbase = qkv2 + (size_t)(b * NO + h * NCH) * NSP;
    const __bf16* kbase = qkv2 + (size_t)(b * NO + 192 + h * NCH) * NSP;
    int nb0 = blockIdx.x * 1024 + w * 256;
    for (int ks = 0; ks < 8; ++ks) {
        int nb = nb0 + ks * 32 + lg * 8;
        bf16x8 a[3], bb[3];
        for (int mf = 0; mf < 3; ++mf)
            a[mf] = *reinterpret_cast<const bf16x8*>(qbase + (size_t)(mf * 16 + lr) * NSP + nb);
        for (int nf = 0; nf < 3; ++nf)
            bb[nf] = *reinterpret_cast<const bf16x8*>(kbase + (size_t)(nf * 16 + lr) * NSP + nb);
        for (int mf = 0; mf < 3; ++mf)
            for (int nf = 0; nf < 3; ++nf)
                acc[mf][nf] = __builtin_amdgcn_mfma_f32_16x16x32_bf16(a[mf], bb[nf], acc[mf][nf], 0, 0, 0);
    }
    __shared__ float red[4][48][49];
    for (int mf = 0; mf < 3; ++mf)
        for (int nf = 0; nf < 3; ++nf)
            for (int r = 0; r < 4; ++r) {
                int c = mf * 16 + lg * 4 + r, d = nf * 16 + lr;
                red[w][c][d] = acc[mf][nf][r];
            }
    __syncthreads();
    float* Sb = S + (size_t)(b * NHEADS + h) * NCH * NCH;
    for (int i = 0; i < 9; ++i) {
        int idx = tid + i * 256;
        int c = idx / 48, d = idx % 48;
        float s = red[0][c][d] + red[1][c][d] + red[2][c][d] + red[3][c][d];
        atomicAdd(&Sb[c * 48 + d], s);
    }
}

// ---------------- kernel 7: normalize + softmax + fold proj: M[b] = w_proj @ blockdiag(attn) ----------------
__global__ __launch_bounds__(256) void k_soft(const float* __restrict__ S, const float* __restrict__ ssq,
                                              const float* __restrict__ temp, const float* __restrict__ w_proj,
                                              __bf16* __restrict__ M) {
    int b = blockIdx.x / NHEADS, h = blockIdx.x % NHEADS;
    int tid = threadIdx.x;
    __shared__ float attn[48][48];
    __shared__ float inv[96];
    if (tid < 96) {
        int c = tid % 48;
        int isK = tid / 48;
        float v = ssq[b * 384 + isK * 192 + h * NCH + c];
        float nrm = fmaxf(sqrtf(v), 1e-12f);
        inv[tid] = 1.f / nrm;
    }
    __syncthreads();
    float tp = temp[h];
    const float* Sb = S + (size_t)(b * NHEADS + h) * NCH * NCH;
    for (int i = 0; i < 9; ++i) {
        int idx = tid + i * 256;
        int c = idx / 48, d = idx % 48;
        attn[c][d] = Sb[c * 48 + d] * inv[c] * inv[48 + d] * tp;
    }
    __syncthreads();
    if (tid < 48) {
        float m = -1e30f;
        for (int d = 0; d < 48; ++d) m = fmaxf(m, attn[tid][d]);
        float sum = 0.f;
        for (int d = 0; d < 48; ++d) { float e = __expf(attn[tid][d] - m); attn[tid][d] = e; sum += e; }
        float r = 1.f / sum;
        for (int d = 0; d < 48; ++d) attn[tid][d] *= r;
    }
    __syncthreads();
    for (int i = 0; i < 36; ++i) {
        int idx = tid + i * 256;
        int oo = idx / 48, d = idx % 48;
        const float* wp = w_proj + oo * NC + h * NCH;
        float s = 0.f;
        for (int c = 0; c < 48; ++c) s += wp[c] * attn[c][d];
        M[(size_t)(b * NC + oo) * NC + h * NCH + d] = (__bf16)s;
    }
}

// ---------------- kernel 8: final GEMM: out[b,o,n] = sum_c' M[b,o,c'] * v[b,c',n] ----------------
__global__ __launch_bounds__(256) void k_out(const __bf16* __restrict__ Mw, const __bf16* __restrict__ qkv2,
                                             float* __restrict__ outp) {
    int b = blockIdx.z;
    int o0 = blockIdx.x * 64;
    int n0blk = blockIdx.y * 128;
    __shared__ __align__(16) __bf16 lds[64 * 200];
    int tid = threadIdx.x;
    const __bf16* msrc = Mw + (size_t)(b * NC + o0) * NC;
    for (int i = 0; i < 6; ++i) {
        int ch = tid + i * 256;
        int r = ch / 24, c8 = (ch % 24) * 8;
        bf16x8 v = *reinterpret_cast<const bf16x8*>(msrc + r * NC + c8);
        *reinterpret_cast<bf16x8*>(&lds[r * 200 + c8]) = v;
    }
    __syncthreads();
    int w = tid >> 6, l = tid & 63, lr = l & 15, lg = l >> 4;
    int n0 = n0blk + w * 32;
    const __bf16* vbase = qkv2 + (size_t)(b * NO + 384) * NSP;
    f32x4 acc[4][2] = {};
    for (int ks = 0; ks < 6; ++ks) {
        int k0 = ks * 32;
        bf16x8 a[4];
        for (int mf = 0; mf < 4; ++mf)
            a[mf] = *reinterpret_cast<const bf16x8*>(&lds[(mf * 16 + lr) * 200 + k0 + lg * 8]);
        bf16x8 bb[2];
        for (int nf = 0; nf < 2; ++nf) {
            const __bf16* vp = vbase + (size_t)(k0 + lg * 8) * NSP + n0 + nf * 16 + lr;
            bf16x8 t;
            for (int j = 0; j < 8; ++j) t[j] = vp[(size_t)j * NSP];
            bb[nf] = t;
        }
        for (int mf = 0; mf < 4; ++mf)
            for (int nf = 0; nf < 2; ++nf)
                acc[mf][nf] = __builtin_amdgcn_mfma_f32_16x16x32_bf16(a[mf], bb[nf], acc[mf][nf], 0, 0, 0);
    }
    for (int mf = 0; mf < 4; ++mf)
        for (int r = 0; r < 4; ++r) {
            int orow = o0 + mf * 16 + lg * 4 + r;
            for (int nf = 0; nf < 2; ++nf) {
                int n = n0 + nf * 16 + lr;
                outp[(size_t)(b * NC + orow) * NSP + n] = acc[mf][nf][r];
            }
        }
}

extern "C" void kernel_launch(void* const* d_in, const int* in_sizes, int n_in,
                              void* d_out, int out_size, void* d_ws, size_t ws_size,
                              hipStream_t stream) {
    const float* x        = (const float*)d_in[0];
    const float* prior    = (const float*)d_in[1];
    const float* w_qkv    = (const float*)d_in[2];
    const float* w_dw     = (const float*)d_in[3];
    const float* w_proj   = (const float*)d_in[4];
    const float* w_kernel = (const float*)d_in[5];
    const float* temp     = (const float*)d_in[6];
    char* ws = (char*)d_ws;
    float*  kv    = (float*)(ws + OFF_KV);
    float*  ssq   = (float*)(ws + OFF_SSQ);
    float*  S     = (float*)(ws + OFF_S);
    __bf16* Wb    = (__bf16*)(ws + OFF_WB);
    __bf16* M     = (__bf16*)(ws + OFF_M);
    __bf16* xt    = (__bf16*)(ws + OFF_XT);
    __bf16* qkv2  = (__bf16*)(ws + OFF_XT);   // aliases xt (xt dead after k_qkv)
    __bf16* qkv1  = (__bf16*)(ws + OFF_QKV1);
    float*  outp  = (float*)d_out;

    // zero atomic accumulators (ssq + S contiguous)
    hipMemsetAsync(ws + OFF_SSQ, 0, 12288 + 294912, stream);

    k_kv<<<12, 256, 0, stream>>>(prior, w_kernel, kv);
    k_wcast<<<432, 256, 0, stream>>>(w_qkv, Wb);
    k_xt<<<dim3(128, 8), 256, 0, stream>>>(x, kv, xt);
    k_qkv<<<dim3(9, 128, 8), 256, 0, stream>>>(xt, Wb, qkv1);
    k_dw<<<9216, 256, 0, stream>>>(qkv1, w_dw, qkv2, ssq);
    k_sdot<<<dim3(16, 4, 8), 256, 0, stream>>>(qkv2, S);
    k_soft<<<32, 256, 0, stream>>>(S, ssq, temp, w_proj, M);
    k_out<<<dim3(3, 128, 8), 256, 0, stream>>>(M, qkv2, outp);
}